// Round 2
// baseline (904.539 us; speedup 1.0000x reference)
//
#include <hip/hip_runtime.h>
#include <math.h>

#define N_CAPS 64
#define IN_CAPS 4096
#define CAP_DIM 32
#define IN_DIM 16
#define EPS 1e-7f

typedef float f32x4 __attribute__((ext_vector_type(4)));

// ws layout (floats):
//   u:     [0, 8388608)                      = 32 MB  (64*4096*32)
//   reduction area at RED_BASE:
//     s_acc0(2048) s_acc1(2048) s_acc2(2048) Z1(64) Z2(64) bar(1)
static constexpr size_t U_ELEMS   = (size_t)N_CAPS * IN_CAPS * CAP_DIM; // 8388608
static constexpr size_t RED_BASE  = U_ELEMS;
static constexpr size_t OFF_SACC0 = 0;
static constexpr size_t OFF_SACC1 = 2048;
static constexpr size_t OFF_SACC2 = 4096;
static constexpr size_t OFF_Z1    = 6144;
static constexpr size_t OFF_Z2    = 6208;
static constexpr size_t OFF_BAR   = 6272;
static constexpr int    RED_TOTAL = 6273; // floats (incl. barrier word)

#define NBLK 512   // routing grid: 64 n * 8 chunks

// ---------------------------------------------------------------------------
// u[n,i,d] = dot(W[n,i,d,0:16], x[i,0:16]).  (unchanged — W-read-bound)
// Coalesced scheme: each wave owns 64 consecutive output elements = 4 KB of W.
// Round r: lane L loads float4 #(r*64+L) of the wave's W chunk (lane-contiguous
// 1 KB per instruction, nontemporal). Lane L holds quarter (L&3) of local
// element r*16+(L>>2); dot4 against the x-quarter from LDS, then
// shfl_xor(1)+shfl_xor(2) butterfly sums the 4 quarter-dots within the quad.
__global__ __launch_bounds__(256) void compute_u_kernel(
        const float* __restrict__ W, const float* __restrict__ x,
        float* __restrict__ u) {
    __shared__ __align__(16) float xs[8 * IN_DIM]; // 8 i's staged
    const int tid = threadIdx.x;
    const size_t e0 = (size_t)blockIdx.x * 256;
    const int i0 = (int)((e0 >> 5) & (IN_CAPS - 1)); // first i of this block
    if (tid < 8 * IN_DIM) xs[tid] = x[(size_t)i0 * IN_DIM + tid];
    __syncthreads();

    const int w = tid >> 6, L = tid & 63, q = L & 3, k = L >> 2;
    const size_t ebase = e0 + (size_t)w * 64;       // wave's first element
    const f32x4* wp = (const f32x4*)W + ebase * 4;  // 4 float4 per element

    float res[4];
    #pragma unroll
    for (int r = 0; r < 4; ++r) {
        f32x4 wv = __builtin_nontemporal_load(wp + r * 64 + L);
        const int le = w * 64 + r * 16 + k;         // local element index
        const f32x4 xv = *(const f32x4*)(xs + (le >> 5) * IN_DIM + q * 4);
        float p = wv.x * xv.x + wv.y * xv.y + wv.z * xv.z + wv.w * xv.w;
        p += __shfl_xor(p, 1, 64);
        p += __shfl_xor(p, 2, 64);
        res[r] = p;
    }
    const float outv = q == 0 ? res[0] : q == 1 ? res[1] : q == 2 ? res[2] : res[3];
    u[ebase + q * 16 + k] = outv;
}

// ---------------------------------------------------------------------------
// Manual grid barrier (cooperative API is a silent no-op under the harness's
// hipGraph stream capture — round-1 lesson).  Safe because co-residency is
// guaranteed: 512 blocks of 256 thr, ~5.5 KB LDS, modest VGPRs -> >=8
// blocks/CU capacity on 256 CUs vs 2 needed.  Monotonic counter, per-phase
// target; only lane 0 spins (agent-scope atomic load + s_sleep backoff).
__device__ __forceinline__ void grid_barrier(unsigned int* bar, unsigned int target) {
    __syncthreads();   // compiler drains vmcnt before s_barrier -> block's
                       // atomics have completed at the coherence point
    if (threadIdx.x == 0) {
        __threadfence();
        __hip_atomic_fetch_add(bar, 1u, __ATOMIC_ACQ_REL, __HIP_MEMORY_SCOPE_AGENT);
        while (__hip_atomic_load(bar, __ATOMIC_ACQUIRE, __HIP_MEMORY_SCOPE_AGENT) < target) {
            __builtin_amdgcn_s_sleep(2);
        }
    }
    __syncthreads();
    __threadfence();   // acquire: invalidate stale L1/L2 lines before re-reads
}

// Agent-scope coherent load: read-back of atomicAdd'd accumulators must not
// hit a stale local (per-XCD) L2 line.
__device__ __forceinline__ float aload(const float* p) {
    return __hip_atomic_load(p, __ATOMIC_RELAXED, __HIP_MEMORY_SCOPE_AGENT);
}

// ---------------------------------------------------------------------------
// Redundant per-block squash: every block re-reads the 8 KB s_acc (LLC-hot)
// and computes the global-norm factor itself — deterministic, so every
// block's private LDS copy of V[n,0:32] stays bitwise identical.
__device__ __forceinline__ void squash_step(
        const float* __restrict__ sacc, const float* __restrict__ Zp,
        float* sred, float* zl, float* vl, int n, int tid,
        float* __restrict__ outp) {
    if (Zp && tid < N_CAPS) zl[tid] = aload(Zp + tid);
    __syncthreads();
    float psum = 0.0f;
    #pragma unroll
    for (int k = 0; k < 8; ++k) {
        const int j = tid + 256 * k;
        const float sc = Zp ? 1.0f / zl[j >> 5] : (1.0f / (float)IN_CAPS);
        const float s = aload(sacc + j) * sc;
        psum += s * s;
    }
    sred[tid] = psum; __syncthreads();
    for (int s = 128; s >= 1; s >>= 1) {
        if (tid < s) sred[tid] += sred[tid + s];
        __syncthreads();
    }
    const float sq = sred[0];
    const float factor = sq / (1.0f + sq) / (sqrtf(sq) + EPS);
    __syncthreads();   // everyone has read sred[0]; safe to reuse sred later
    if (tid < CAP_DIM) {
        const float sc = Zp ? 1.0f / zl[n] : (1.0f / (float)IN_CAPS);
        const float v = aload(sacc + n * CAP_DIM + tid) * sc * factor;
        vl[tid] += v;
        if (outp) outp[n * CAP_DIM + tid] = v;
    }
    __syncthreads();
}

// ---------------------------------------------------------------------------
// Routing pass (512 i's per block): t = dot(u[n,i,:], V[n,:]); w = exp(t);
// Z[n] += sum w;  s_acc[n,d] += sum w*u[n,i,d].
__device__ __forceinline__ void route_step(
        const float* __restrict__ u, size_t ubase, int n, int chunk, int tid,
        const float* vl, float* wbuf, float* sred,
        float* __restrict__ sacc_out, float* __restrict__ Zout) {
    const int ii = tid >> 5, d = tid & 31;
    float zacc = 0.0f, sacc = 0.0f;
    #pragma unroll
    for (int c = 0; c < 2; ++c) {
        const int ib = chunk * 512 + c * 256;
        // phase A: one i per thread, 128B contiguous read of u[n,i,:]
        {
            const f32x4* up = (const f32x4*)(u + ubase + (size_t)(ib + tid) * CAP_DIM);
            const f32x4* vv = (const f32x4*)vl;
            float t = 0.0f;
            #pragma unroll
            for (int q = 0; q < 8; ++q) {
                f32x4 a = up[q], b = vv[q];
                t += a.x * b.x + a.y * b.y + a.z * b.z + a.w * b.w;
            }
            const float w = expf(t);
            wbuf[tid] = w;
            zacc += w;
        }
        __syncthreads();
        // phase B: (ii,d) layout, coalesced re-read (L1/L2-hot)
        {
            const size_t off = ubase + (size_t)ib * CAP_DIM;
            #pragma unroll
            for (int k = 0; k < 32; ++k) {
                const int li = k * 8 + ii;
                sacc += wbuf[li] * u[off + (size_t)li * CAP_DIM + d];
            }
        }
        __syncthreads();
    }
    sred[tid] = sacc; __syncthreads();
    for (int s = 128; s >= 32; s >>= 1) {
        if (tid < s) sred[tid] += sred[tid + s];
        __syncthreads();
    }
    if (tid < 32) atomicAdd(&sacc_out[n * CAP_DIM + tid], sred[tid]);
    __syncthreads();
    sred[tid] = zacc; __syncthreads();
    for (int s = 128; s >= 1; s >>= 1) {
        if (tid < s) sred[tid] += sred[tid + s];
        __syncthreads();
    }
    if (tid == 0) atomicAdd(Zout + n, sred[0]);
    __syncthreads();   // protect sred reuse in next phase
}

// ---------------------------------------------------------------------------
// Fused routing: one normally-launched kernel + manual grid barriers replaces
//   sum_u + squash + route + squash + route + squash  (6 dispatches -> 1).
// Grid = 512 blocks (n = bid>>3, chunk = bid&7 -> 512 i's each), block = 256.
__global__ __launch_bounds__(256) void routing_kernel(
        const float* __restrict__ u,
        float* __restrict__ s0, float* __restrict__ s1, float* __restrict__ s2,
        float* __restrict__ Z1v, float* __restrict__ Z2v,
        unsigned int* __restrict__ bar,
        float* __restrict__ out) {
    __shared__ __align__(16) float sred[1024];   // f32x4[256] sum tree / float[256] reductions
    __shared__ float wbuf[256];
    __shared__ __align__(16) float vl[CAP_DIM];  // this n's accumulated V
    __shared__ float zl[N_CAPS];
    const int tid = threadIdx.x;
    const int bid = blockIdx.x;
    const int n = bid >> 3, chunk = bid & 7;
    const size_t ubase = (size_t)n * IN_CAPS * CAP_DIM;

    if (tid < CAP_DIM) vl[tid] = 0.0f;

    // ---- iter 1: s0[n,d] += sum over this block's 512 i of u[n,i,d]
    {
        const f32x4* up = (const f32x4*)(u + ubase + (size_t)chunk * 512 * CAP_DIM);
        f32x4 a = {0.0f, 0.0f, 0.0f, 0.0f};
        #pragma unroll
        for (int s = 0; s < 16; ++s) a += up[s * 256 + tid];
        // a[j] = partial for d = (tid&7)*4 + j, over i's with i%32 == tid>>3
        f32x4* sv = (f32x4*)sred;
        sv[tid] = a; __syncthreads();
        for (int off = 128; off >= 8; off >>= 1) {
            if (tid < off) sv[tid] += sv[tid + off];
            __syncthreads();
        }
        if (tid < 32) atomicAdd(&s0[n * CAP_DIM + tid], sred[tid]);
    }
    grid_barrier(bar, 1 * NBLK);

    // ---- iter 1 squash -> V, then iter 2 routing pass
    squash_step(s0, nullptr, sred, zl, vl, n, tid, nullptr);
    route_step(u, ubase, n, chunk, tid, vl, wbuf, sred, s1, Z1v);
    grid_barrier(bar, 2 * NBLK);

    // ---- iter 2 squash -> V, then iter 3 routing pass
    squash_step(s1, Z1v, sred, zl, vl, n, tid, nullptr);
    route_step(u, ubase, n, chunk, tid, vl, wbuf, sred, s2, Z2v);
    grid_barrier(bar, 3 * NBLK);

    // ---- iter 3 squash -> output (chunk-0 blocks write)
    squash_step(s2, Z2v, sred, zl, vl, n, tid, (chunk == 0) ? out : nullptr);
}

// ---------------------------------------------------------------------------
extern "C" void kernel_launch(void* const* d_in, const int* in_sizes, int n_in,
                              void* d_out, int out_size, void* d_ws, size_t ws_size,
                              hipStream_t stream) {
    const float* x = (const float*)d_in[0];  // (4096, 16, 1)
    const float* W = (const float*)d_in[1];  // (64, 4096, 32, 16)
    float* out = (float*)d_out;              // (64, 32, 1)
    float* ws  = (float*)d_ws;

    float* u     = ws;
    float* redb  = ws + RED_BASE;
    float* sacc0 = redb + OFF_SACC0;
    float* sacc1 = redb + OFF_SACC1;
    float* sacc2 = redb + OFF_SACC2;
    float* Z1    = redb + OFF_Z1;
    float* Z2    = redb + OFF_Z2;
    unsigned int* bar = (unsigned int*)(redb + OFF_BAR);

    // Zero scratch + barrier word (harness poisons ws with 0xAA every call).
    // hipMemsetAsync is graph-capture-safe (the harness itself uses it).
    hipMemsetAsync(redb, 0, RED_TOTAL * sizeof(float), stream);

    compute_u_kernel<<<(int)(U_ELEMS / 256), 256, 0, stream>>>(W, x, u);

    routing_kernel<<<NBLK, 256, 0, stream>>>(u, sacc0, sacc1, sacc2,
                                             Z1, Z2, bar, out);
}